// Round 14
// baseline (302.800 us; speedup 1.0000x reference)
//
#include <hip/hip_runtime.h>

typedef unsigned short u16;
typedef __attribute__((ext_vector_type(8))) short short8;
typedef __attribute__((ext_vector_type(4))) float f32x4;
typedef __attribute__((ext_vector_type(16))) float f32x16;
typedef __attribute__((ext_vector_type(4))) unsigned uint4v;

#define NTOK 343
#define DIMC 512
#define HEADS_ 16
#define BATCH 128
#define MROWS 43904
#define TBL 117649

#define LOG2E 1.4426950408889634f
#define QSCALE (0.17677669529663687f * LOG2E)  // hd^-0.5 * log2(e), folded into q

__device__ __forceinline__ u16 f2bf(float f) {
  unsigned u = __builtin_bit_cast(unsigned, f);
  unsigned r = (u + 0x7fffu + ((u >> 16) & 1u)) >> 16;
  return (u16)r;
}
__device__ __forceinline__ float bf2f(u16 x) {
  return __builtin_bit_cast(float, ((unsigned)x) << 16);
}
__device__ __forceinline__ unsigned cvtpk(float lo, float hi) {
  unsigned r;
  asm("v_cvt_pk_bf16_f32 %0, %1, %2" : "=v"(r) : "v"(lo), "v"(hi));
  return r;
}

__global__ void cvt_f32_bf16_k(const float* __restrict__ in, u16* __restrict__ out, int n4) {
  int i = blockIdx.x * blockDim.x + threadIdx.x;
  int st = gridDim.x * blockDim.x;
  for (; i < n4; i += st) {
    float4 v = reinterpret_cast<const float4*>(in)[i];
    ushort4 o;
    o.x = f2bf(v.x); o.y = f2bf(v.y); o.z = f2bf(v.z); o.w = f2bf(v.w);
    reinterpret_cast<ushort4*>(out)[i] = o;
  }
}

// 32x32 fragment bias: biasB[((h*11 + nt)*11 + tq)*1024 + l*16 + r] =
//   bf16(log2e * bias(h, q = tq*32 + (l&31), tok = nt*32 + (r&3)+8*(r>>2)+4*(l>>5)))
//   or -1e30 when q/tok out of range (masks pads).
__global__ void bias_pre_k(const float* __restrict__ table, const int* __restrict__ idx,
                           u16* __restrict__ biasB) {
  int t = blockIdx.x * 256 + threadIdx.x;
  if (t >= HEADS_ * 121 * 256) return;  // 495,616
  int r4 = t & 3;
  int l = (t >> 2) & 63;
  int rest = t >> 8;
  int tq = rest % 11;
  int nt = (rest / 11) % 11;
  int h = rest / 121;
  int q = tq * 32 + (l & 31);
  int hi = l >> 5;
  ushort4 o;
  u16* oe = (u16*)&o;
#pragma unroll
  for (int rr = 0; rr < 4; ++rr) {
    int r = r4 * 4 + rr;
    int tok = nt * 32 + (r & 3) + 8 * (r >> 2) + 4 * hi;
    float v = (q < NTOK && tok < NTOK) ? (LOG2E * table[idx[q * NTOK + tok] * HEADS_ + h])
                                       : -1e30f;
    oe[rr] = f2bf(v);
  }
  *reinterpret_cast<ushort4*>(biasB +
                              (size_t)(((h * 11 + nt) * 11 + tq) * 1024 + l * 16 + r4 * 4)) = o;
}

#define GLD16(gptr, lptr)                                                        \
  __builtin_amdgcn_global_load_lds(                                              \
      (const __attribute__((address_space(1))) void*)(const void*)(gptr),        \
      (__attribute__((address_space(3))) void*)(void*)(lptr), 16, 0, 0)

// C = A @ B^T (+bias).  B: [N][K] bf16 (K-contiguous).
// R11 structure: 128x128 tile, BK=32, 2-slot dbuf, STG(next) before compute.
// EPI 0: A = x fp32 [M][K] staged fp32 via gload_lds (16 KB/slot); convert fused into
//        fragment read (2 x float4 + 4 cvt_pk); swizzle on 16B-blk ^ (row&7), source
//        pre-swizzled (rule 21). bf16 out (+bias, QSCALE). LDS 48 KB -> 3 blocks/CU.
// EPI 1: A bf16, R11-exact path (24 KB LDS).
template <int EPI>
__global__ __launch_bounds__(256) void gemm_bt_k(const void* __restrict__ Av,
                                                 const u16* __restrict__ B,
                                                 const float* __restrict__ bias,
                                                 void* __restrict__ C, int N, int K) {
  const int NBL = N >> 7;
  int nwg = gridDim.x;
  int orig = blockIdx.x;
  int qq = nwg >> 3, rr = nwg & 7;
  int xcd = orig & 7, lid = orig >> 3;
  int bid = (xcd < rr ? xcd * (qq + 1) : rr * (qq + 1) + (xcd - rr) * qq) + lid;
  int mb = bid / NBL, nb = bid % NBL;
  __shared__ __align__(16) char AsRaw[EPI == 0 ? 32768 : 16384];
  __shared__ __align__(16) u16 Bs[2][128 * 32];
  float* AsF = (float*)AsRaw;       // EPI0: [2][128*32] fp32
  u16* AsB = (u16*)AsRaw;           // EPI1: [2][128*32] bf16
  int tid = threadIdx.x;
  int w = tid >> 6, l = tid & 63;
  int wr = w >> 1, wc = w & 1;
  int cl = l & 15, q4 = l >> 4;
  f32x4 acc[4][4];
#pragma unroll
  for (int i = 0; i < 4; i++)
#pragma unroll
    for (int j = 0; j < 4; j++) acc[i][j] = (f32x4){0.f, 0.f, 0.f, 0.f};

  const int srow_in = l >> 2;   // B staging: row within 16-row chunk
  const int scb = l & 3;

  // A fp32 staging: 4 ops x (8 rows x 128 B); row = w*32+i4*8+(l>>3), blk = l&7
#define STGA32(kt, slot)                                                                  \
  {                                                                                       \
    _Pragma("unroll") for (int i4 = 0; i4 < 4; ++i4) {                                    \
      int rowl = w * 32 + i4 * 8 + (l >> 3);                                              \
      int blk = (l & 7) ^ (rowl & 7); /* inverse swizzle on SOURCE */                     \
      GLD16((const float*)Av + (size_t)(mb * 128 + rowl) * K + (kt)*32 + blk * 4,         \
            AsF + (slot)*4096 + (w * 32 + i4 * 8) * 32 + l * 4);                          \
    }                                                                                     \
  }
  // A bf16 staging (EPI1, R11-exact)
#define STGA16(kt, slot)                                                                  \
  {                                                                                       \
    _Pragma("unroll") for (int i4 = 0; i4 < 2; ++i4) {                                    \
      int rowl = w * 32 + i4 * 16 + srow_in;                                              \
      int cbs = (scb * 16) ^ (((rowl >> 1) & 3) << 4);                                    \
      GLD16((const u16*)Av + (size_t)(mb * 128 + rowl) * K + (kt)*32 + (cbs >> 1),        \
            AsB + (slot)*4096 + (w * 32 + i4 * 16) * 32 + l * 8);                         \
    }                                                                                     \
  }
#define STGB(kt, slot)                                                                    \
  {                                                                                       \
    _Pragma("unroll") for (int i4 = 0; i4 < 2; ++i4) {                                    \
      int rowl = w * 32 + i4 * 16 + srow_in;                                              \
      int cbs = (scb * 16) ^ (((rowl >> 1) & 3) << 4);                                    \
      GLD16(B + (size_t)(nb * 128 + rowl) * K + (kt)*32 + (cbs >> 1),                     \
            Bs[slot] + (w * 32 + i4 * 16) * 32 + l * 8);                                  \
    }                                                                                     \
  }
#define STG2(kt, slot)                                 \
  {                                                    \
    if (EPI == 0) STGA32(kt, slot) else STGA16(kt, slot) \
    STGB(kt, slot)                                     \
  }

  int KT = K >> 5;
  STG2(0, 0);
  __syncthreads();  // tile 0 resident
  for (int kt = 0; kt < KT; ++kt) {
    int cur = kt & 1;
    if (kt + 1 < KT) STG2(kt + 1, cur ^ 1);  // issue next-tile loads FIRST
    {
      short8 af[4], bf[4];
#pragma unroll
      for (int i = 0; i < 4; i++) {
        int row = wr * 64 + i * 16 + cl;
        if (EPI == 0) {
          const float* Ap = AsF + cur * 4096 + row * 32;
          int b0 = (2 * q4) ^ (row & 7), b1 = (2 * q4 + 1) ^ (row & 7);
          float4 a0 = *reinterpret_cast<const float4*>(Ap + b0 * 4);
          float4 a1 = *reinterpret_cast<const float4*>(Ap + b1 * 4);
          uint4v ua;
          ua.x = cvtpk(a0.x, a0.y);
          ua.y = cvtpk(a0.z, a0.w);
          ua.z = cvtpk(a1.x, a1.y);
          ua.w = cvtpk(a1.z, a1.w);
          af[i] = __builtin_bit_cast(short8, ua);
        } else {
          int off = row * 64 + ((q4 * 16) ^ (((row >> 1) & 3) << 4));  // byte addr
          af[i] = *reinterpret_cast<const short8*>(AsB + cur * 4096 + (off >> 1));
        }
      }
#pragma unroll
      for (int j = 0; j < 4; j++) {
        int row = wc * 64 + j * 16 + cl;
        int off = row * 64 + ((q4 * 16) ^ (((row >> 1) & 3) << 4));
        bf[j] = *reinterpret_cast<const short8*>((const u16*)Bs[cur] + (off >> 1));
      }
#pragma unroll
      for (int i = 0; i < 4; i++)
#pragma unroll
        for (int j = 0; j < 4; j++)
          acc[i][j] = __builtin_amdgcn_mfma_f32_16x16x32_bf16(af[i], bf[j], acc[i][j], 0, 0, 0);
    }
    __syncthreads();
  }
#undef STG2
#undef STGA32
#undef STGA16
#undef STGB

  int r0 = mb * 128 + wr * 64 + q4 * 4;
  int c0 = nb * 128 + wc * 64 + cl;
#pragma unroll
  for (int j = 0; j < 4; j++) {
    int col = c0 + j * 16;
    float bv = bias[col];
    float mul = (EPI == 0 && col < 512) ? QSCALE : 1.0f;
#pragma unroll
    for (int i = 0; i < 4; i++) {
      int row = r0 + i * 16;
      if (EPI == 0) {
        u16* Cp = (u16*)C + (size_t)row * N + col;
#pragma unroll
        for (int r = 0; r < 4; r += 2) {
          unsigned pk = cvtpk((acc[i][j][r] + bv) * mul, (acc[i][j][r + 1] + bv) * mul);
          Cp[(size_t)r * N] = (u16)pk;
          Cp[(size_t)(r + 1) * N] = (u16)(pk >> 16);
        }
      } else {
#pragma unroll
        for (int r = 0; r < 4; r++)
          ((float*)C)[(size_t)(row + r) * N + col] = acc[i][j][r] + bv;
      }
    }
  }
}

// One block per (b,h). LDS 51.8 KB -> 3 blocks/CU. 32x32x16-MFMA scheme (R10/R12).
// V transpose staged via PAIRED-LANE u32 writes (shfl_xor(4): rows r,r+1 packed) —
// halves the scalar ds_write count that caused the ~1.2e7 bank-conflict cycles.
__global__ __launch_bounds__(256, 3) void attn_k(const u16* __restrict__ qkv,
                                                 const u16* __restrict__ biasB,
                                                 u16* __restrict__ outA) {
  int p = blockIdx.x;
  int jj = p >> 3;
  int h = 2 * (p & 7) + (jj >> 7);
  int b = jj & 127;
  __shared__ __align__(16) u16 kS[352 * 40];   // rows=tok, 80 B rows (odd*16B)
  __shared__ __align__(16) u16 vT[32 * 370];   // [d][tok]
  int tid = threadIdx.x;

  for (int idx = tid; idx < 352 * 4; idx += 256) {
    int row = idx >> 2, seg = idx & 3;
    uint4 vk = {0, 0, 0, 0};
    if (row < NTOK)
      vk = *reinterpret_cast<const uint4*>(qkv + (size_t)(b * NTOK + row) * 1536 + 512 +
                                           h * 32 + seg * 8);
    *reinterpret_cast<uint4*>(kS + row * 40 + seg * 8) = vk;
  }
  // V transpose: lane pairs (l, l^4) hold rows (r, r^1); pack tok-pairs into u32 writes.
  for (int idx = tid; idx < 344 * 4; idx += 256) {
    int row = idx >> 2, seg = idx & 3;
    uint4 vv = {0, 0, 0, 0};
    if (row < NTOK)
      vv = *reinterpret_cast<const uint4*>(qkv + (size_t)(b * NTOK + row) * 1536 + 1024 +
                                           h * 32 + seg * 8);
    unsigned ox = (unsigned)__shfl_xor((int)vv.x, 4);
    unsigned oy = (unsigned)__shfl_xor((int)vv.y, 4);
    unsigned oz = (unsigned)__shfl_xor((int)vv.z, 4);
    unsigned ow = (unsigned)__shfl_xor((int)vv.w, 4);
    unsigned* vT32 = (unsigned*)vT;
    int rp = row >> 1;
    if ((row & 1) == 0) {
      int d0 = seg * 8;
      vT32[(d0 + 0) * 185 + rp] = (vv.x & 0xFFFFu) | (ox << 16);
      vT32[(d0 + 1) * 185 + rp] = (vv.x >> 16) | (ox & 0xFFFF0000u);
      vT32[(d0 + 2) * 185 + rp] = (vv.y & 0xFFFFu) | (oy << 16);
      vT32[(d0 + 3) * 185 + rp] = (vv.y >> 16) | (oy & 0xFFFF0000u);
    } else {
      int d0 = seg * 8 + 4;
      vT32[(d0 + 0) * 185 + rp] = (oz & 0xFFFFu) | (vv.z << 16);
      vT32[(d0 + 1) * 185 + rp] = (oz >> 16) | (vv.z & 0xFFFF0000u);
      vT32[(d0 + 2) * 185 + rp] = (ow & 0xFFFFu) | (vv.w << 16);
      vT32[(d0 + 3) * 185 + rp] = (ow >> 16) | (vv.w & 0xFFFF0000u);
    }
  }
  for (int idx = tid; idx < 32 * 8; idx += 256) vT[(idx / 8) * 370 + 344 + (idx % 8)] = 0;
  __syncthreads();

  int w = tid >> 6, l = tid & 63;
  const int d32 = l & 31, hi = l >> 5;
  const bool upHalf = (hi != 0);

  for (int tq = w; tq < 11; tq += 4) {
    int qrow = tq * 32 + d32;
    short8 bq0 = (short8){0, 0, 0, 0, 0, 0, 0, 0};
    short8 bq1 = (short8){0, 0, 0, 0, 0, 0, 0, 0};
    if (qrow < NTOK) {
      const u16* qb = qkv + (size_t)(b * NTOK + qrow) * 1536 + h * 32 + hi * 8;
      bq0 = *reinterpret_cast<const short8*>(qb);
      bq1 = *reinterpret_cast<const short8*>(qb + 16);
    }
    f32x16 O = {0, 0, 0, 0, 0, 0, 0, 0, 0, 0, 0, 0, 0, 0, 0, 0};
    float tot = 0.f;
    const u16* bbase = biasB + ((size_t)(h * 121 + tq)) * 1024 + l * 16;  // + nt*11*1024
    for (int nt = 0; nt < 11; ++nt) {
      const u16* kr = kS + (nt * 32 + d32) * 40 + hi * 8;
      short8 ak0 = *reinterpret_cast<const short8*>(kr);       // dims hi*8..+7
      short8 ak1 = *reinterpret_cast<const short8*>(kr + 16);  // dims 16+hi*8..+7
      f32x16 S = {0, 0, 0, 0, 0, 0, 0, 0, 0, 0, 0, 0, 0, 0, 0, 0};
      S = __builtin_amdgcn_mfma_f32_32x32x16_bf16(ak0, bq0, S, 0, 0, 0);
      S = __builtin_amdgcn_mfma_f32_32x32x16_bf16(ak1, bq1, S, 0, 0, 0);
      const u16* bp = bbase + (size_t)nt * 11 * 1024;
      short8 bb0 = *reinterpret_cast<const short8*>(bp);
      short8 bb1 = *reinterpret_cast<const short8*>(bp + 8);
      float ex[16];
#pragma unroll
      for (int r = 0; r < 16; ++r) {
        u16 bw = (u16)((r < 8) ? bb0[r] : bb1[r - 8]);
        float v = S[r] + bf2f(bw);
        ex[r] = __builtin_amdgcn_exp2f(v);
        tot += ex[r];
      }
      unsigned W[8];
#pragma unroll
      for (int r2 = 0; r2 < 8; ++r2) W[r2] = cvtpk(ex[2 * r2], ex[2 * r2 + 1]);
#pragma unroll
      for (int c = 0; c < 2; ++c) {
        unsigned x0 = W[4 * c + 0], x1 = W[4 * c + 1];
        unsigned y0 = W[4 * c + 2], y1 = W[4 * c + 3];
        unsigned x0s = (unsigned)__shfl_xor((int)x0, 32);
        unsigned x1s = (unsigned)__shfl_xor((int)x1, 32);
        unsigned y0s = (unsigned)__shfl_xor((int)y0, 32);
        unsigned y1s = (unsigned)__shfl_xor((int)y1, 32);
        uint4v ap;
        ap.x = upHalf ? y0s : x0;
        ap.y = upHalf ? y1s : x1;
        ap.z = upHalf ? y0 : x0s;
        ap.w = upHalf ? y1 : x1s;
        short8 bv = *reinterpret_cast<const short8*>(vT + d32 * 370 + nt * 32 + c * 16 + hi * 8);
        O = __builtin_amdgcn_mfma_f32_32x32x16_bf16(__builtin_bit_cast(short8, ap), bv, O,
                                                    0, 0, 0);
      }
    }
    tot += __builtin_bit_cast(float, __shfl_xor(__builtin_bit_cast(int, tot), 32));
    float inv = 1.0f / tot;
#pragma unroll
    for (int r = 0; r < 16; ++r) {
      int qloc = (r & 3) + 8 * (r >> 2) + 4 * hi;
      float ir = __shfl(inv, qloc);
      int q = tq * 32 + qloc;
      if (q < NTOK) {
        float ov = O[r] * ir;
        outA[(size_t)(b * NTOK + q) * 512 + h * 32 + d32] = (u16)cvtpk(ov, ov);
      }
    }
  }
}

extern "C" void kernel_launch(void* const* d_in, const int* in_sizes, int n_in,
                              void* d_out, int out_size, void* d_ws, size_t ws_size,
                              hipStream_t stream) {
  const float* x      = (const float*)d_in[0];
  // d_in[1] = q_global: unused by reference
  const float* qkv_w  = (const float*)d_in[2];
  const float* qkv_b  = (const float*)d_in[3];
  const float* table  = (const float*)d_in[4];
  const float* proj_w = (const float*)d_in[5];
  const float* proj_b = (const float*)d_in[6];
  const int*   relidx = (const int*)d_in[7];

  char* ws = (char*)d_ws;
  u16*   attnO = (u16*)(ws);                 // 44,957,696 B (attn output, bf16)
  u16*   qw_bf = (u16*)(ws + 44957696);      //  1,572,864 B
  u16*   pw_bf = (u16*)(ws + 46530560);      //    524,288 B
  u16*   qkv_o = (u16*)(ws + 47054848);      // 134,873,088 B
  u16*   biasB = (u16*)(ws + 181927936);     //  3,964,928 B (16*11*11*1024 u16)

  cvt_f32_bf16_k<<<768, 256, 0, stream>>>(qkv_w, qw_bf, (3 * DIMC * DIMC) / 4);
  cvt_f32_bf16_k<<<256, 256, 0, stream>>>(proj_w, pw_bf, (DIMC * DIMC) / 4);
  bias_pre_k<<<1936, 256, 0, stream>>>(table, relidx, biasB);

  gemm_bt_k<0><<<343 * 12, 256, 0, stream>>>(x, qw_bf, qkv_b, qkv_o, 1536, 512);
  attn_k<<<BATCH * HEADS_, 256, 0, stream>>>(qkv_o, biasB, attnO);
  gemm_bt_k<1><<<343 * 4, 256, 0, stream>>>(attnO, pw_bf, proj_b, d_out, 512, 512);
}

// Round 15
// 250.258 us; speedup vs baseline: 1.2100x; 1.2100x over previous
//
#include <hip/hip_runtime.h>

typedef unsigned short u16;
typedef __attribute__((ext_vector_type(8))) short short8;
typedef __attribute__((ext_vector_type(4))) float f32x4;
typedef __attribute__((ext_vector_type(16))) float f32x16;
typedef __attribute__((ext_vector_type(4))) unsigned uint4v;

#define NTOK 343
#define DIMC 512
#define HEADS_ 16
#define BATCH 128
#define MROWS 43904
#define TBL 117649

#define LOG2E 1.4426950408889634f
#define QSCALE (0.17677669529663687f * LOG2E)  // hd^-0.5 * log2(e), folded into q

__device__ __forceinline__ u16 f2bf(float f) {
  unsigned u = __builtin_bit_cast(unsigned, f);
  unsigned r = (u + 0x7fffu + ((u >> 16) & 1u)) >> 16;
  return (u16)r;
}
__device__ __forceinline__ float bf2f(u16 x) {
  return __builtin_bit_cast(float, ((unsigned)x) << 16);
}
__device__ __forceinline__ unsigned cvtpk(float lo, float hi) {
  unsigned r;
  asm("v_cvt_pk_bf16_f32 %0, %1, %2" : "=v"(r) : "v"(lo), "v"(hi));
  return r;
}

__global__ void cvt_f32_bf16_k(const float* __restrict__ in, u16* __restrict__ out, int n4) {
  int i = blockIdx.x * blockDim.x + threadIdx.x;
  int st = gridDim.x * blockDim.x;
  for (; i < n4; i += st) {
    float4 v = reinterpret_cast<const float4*>(in)[i];
    ushort4 o;
    o.x = f2bf(v.x); o.y = f2bf(v.y); o.z = f2bf(v.z); o.w = f2bf(v.w);
    reinterpret_cast<ushort4*>(out)[i] = o;
  }
}

// Merged prep: blocks [0,768) convert qkv_w (exact), [768,1024) convert proj_w (exact),
// [1024,2960) build the 32x32-fragment bias table:
// biasB[((h*11 + nt)*11 + tq)*1024 + l*16 + r] = bf16(log2e * bias(h, q=tq*32+(l&31),
//   tok = nt*32 + (r&3)+8*(r>>2)+4*(l>>5))), or -1e30 when q/tok OOR.
__global__ void prep_k(const float* __restrict__ qw, u16* __restrict__ qwb,
                       const float* __restrict__ pw, u16* __restrict__ pwb,
                       const float* __restrict__ table, const int* __restrict__ idx,
                       u16* __restrict__ biasB) {
  int bidx = blockIdx.x;
  if (bidx < 1024) {
    const float* in = bidx < 768 ? qw : pw;
    u16* out = bidx < 768 ? qwb : pwb;
    int i = (bidx < 768 ? bidx : bidx - 768) * 256 + threadIdx.x;
    float4 v = reinterpret_cast<const float4*>(in)[i];
    ushort4 o;
    o.x = f2bf(v.x); o.y = f2bf(v.y); o.z = f2bf(v.z); o.w = f2bf(v.w);
    reinterpret_cast<ushort4*>(out)[i] = o;
    return;
  }
  int t = (bidx - 1024) * 256 + threadIdx.x;
  if (t >= HEADS_ * 121 * 256) return;  // 495,616
  int r4 = t & 3;
  int l = (t >> 2) & 63;
  int rest = t >> 8;
  int tq = rest % 11;
  int nt = (rest / 11) % 11;
  int h = rest / 121;
  int q = tq * 32 + (l & 31);
  int hi = l >> 5;
  ushort4 o;
  u16* oe = (u16*)&o;
#pragma unroll
  for (int rr = 0; rr < 4; ++rr) {
    int r = r4 * 4 + rr;
    int tok = nt * 32 + (r & 3) + 8 * (r >> 2) + 4 * hi;
    float v = (q < NTOK && tok < NTOK) ? (LOG2E * table[idx[q * NTOK + tok] * HEADS_ + h])
                                       : -1e30f;
    oe[rr] = f2bf(v);
  }
  *reinterpret_cast<ushort4*>(biasB +
                              (size_t)(((h * 11 + nt) * 11 + tq) * 1024 + l * 16 + r4 * 4)) = o;
}

#define GLD16(gptr, lptr)                                                        \
  __builtin_amdgcn_global_load_lds(                                              \
      (const __attribute__((address_space(1))) void*)(const void*)(gptr),        \
      (__attribute__((address_space(3))) void*)(void*)(lptr), 16, 0, 0)

// C = A @ B^T (+bias).  A: [M][K] bf16, B: [N][K] bf16 (K-contiguous).
// R10-exact GEMM (best measured config): 128x128 tile, BK=64, 2-slot dbuf LDS (64 KB),
// STG(next) issued before compute; T2 swizzle triple (rule 21).
template <int EPI>
__global__ __launch_bounds__(256) void gemm_bt_k(const u16* __restrict__ A,
                                                 const u16* __restrict__ B,
                                                 const float* __restrict__ bias,
                                                 void* __restrict__ C, int N, int K) {
  const int NBL = N >> 7;
  int nwg = gridDim.x;
  int orig = blockIdx.x;
  int qq = nwg >> 3, rr = nwg & 7;
  int xcd = orig & 7, lid = orig >> 3;
  int bid = (xcd < rr ? xcd * (qq + 1) : rr * (qq + 1) + (xcd - rr) * qq) + lid;
  int mb = bid / NBL, nb = bid % NBL;
  __shared__ __align__(16) u16 As[2][128 * 64];
  __shared__ __align__(16) u16 Bs[2][128 * 64];
  int tid = threadIdx.x;
  int w = tid >> 6, l = tid & 63;
  int wr = w >> 1, wc = w & 1;
  f32x4 acc[4][4];
#pragma unroll
  for (int i = 0; i < 4; i++)
#pragma unroll
    for (int j = 0; j < 4; j++) acc[i][j] = (f32x4){0.f, 0.f, 0.f, 0.f};

  const int l8r = l >> 3, l8c = l & 7;
  const int woff = (w * 32) * 64;

#define STG2(kt, slot)                                                                    \
  {                                                                                       \
    _Pragma("unroll") for (int i4 = 0; i4 < 4; ++i4) {                                    \
      int rowl = w * 32 + i4 * 8 + l8r;                                                   \
      int cbs = (l8c * 16) ^ (((rowl >> 1) & 7) << 4); /* inverse swizzle on SOURCE */    \
      GLD16(A + (size_t)(mb * 128 + rowl) * K + (kt)*64 + (cbs >> 1),                     \
            As[slot] + woff + i4 * 512 + l * 8);                                          \
      GLD16(B + (size_t)(nb * 128 + rowl) * K + (kt)*64 + (cbs >> 1),                     \
            Bs[slot] + woff + i4 * 512 + l * 8);                                          \
    }                                                                                     \
  }

  int KT = K >> 6;
  STG2(0, 0);
  __syncthreads();
  for (int kt = 0; kt < KT; ++kt) {
    int cur = kt & 1;
    if (kt + 1 < KT) STG2(kt + 1, cur ^ 1);
#pragma unroll
    for (int kk = 0; kk < 2; ++kk) {
      short8 af[4], bf[4];
#pragma unroll
      for (int i = 0; i < 4; i++) {
        int off = (wr * 64 + i * 16 + (l & 15)) * 128 + kk * 64 + (l >> 4) * 16;
        off ^= ((off >> 8) & 7) << 4;
        af[i] = *reinterpret_cast<const short8*>((const u16*)As[cur] + (off >> 1));
      }
#pragma unroll
      for (int j = 0; j < 4; j++) {
        int off = (wc * 64 + j * 16 + (l & 15)) * 128 + kk * 64 + (l >> 4) * 16;
        off ^= ((off >> 8) & 7) << 4;
        bf[j] = *reinterpret_cast<const short8*>((const u16*)Bs[cur] + (off >> 1));
      }
#pragma unroll
      for (int i = 0; i < 4; i++)
#pragma unroll
        for (int j = 0; j < 4; j++)
          acc[i][j] = __builtin_amdgcn_mfma_f32_16x16x32_bf16(af[i], bf[j], acc[i][j], 0, 0, 0);
    }
    __syncthreads();
  }
#undef STG2

  int r0 = mb * 128 + wr * 64 + (l >> 4) * 4;
  int c0 = nb * 128 + wc * 64 + (l & 15);
#pragma unroll
  for (int j = 0; j < 4; j++) {
    int col = c0 + j * 16;
    float bv = bias[col];
    float mul = (EPI == 0 && col < 512) ? QSCALE : 1.0f;
#pragma unroll
    for (int i = 0; i < 4; i++) {
      int row = r0 + i * 16;
      if (EPI == 0) {
        u16* Cp = (u16*)C + (size_t)row * N + col;
#pragma unroll
        for (int r = 0; r < 4; r += 2) {
          unsigned pk = cvtpk((acc[i][j][r] + bv) * mul, (acc[i][j][r + 1] + bv) * mul);
          Cp[(size_t)r * N] = (u16)pk;
          Cp[(size_t)(r + 1) * N] = (u16)(pk >> 16);
        }
      } else {
#pragma unroll
        for (int r = 0; r < 4; r++)
          ((float*)C)[(size_t)(row + r) * N + col] = acc[i][j][r] + bv;
      }
    }
  }
}

// One block per (b,h). LDS 51.8 KB -> 3 blocks/CU. 32x32x16-MFMA scheme (R10) with a
// 2-stage nt-PIPELINE: K-frags + bias for nt+1 prefetched and S(nt+1)'s MFMAs ISSUED
// before the softmax/pack/PV of nt — MFMA pipe fills the VALU/TRANS exp2 gap (m114).
// Static 2-state (named regs, no runtime indexing — rule #20).
__global__ __launch_bounds__(256, 3) void attn_k(const u16* __restrict__ qkv,
                                                 const u16* __restrict__ biasB,
                                                 u16* __restrict__ outA) {
  int p = blockIdx.x;
  int jj = p >> 3;
  int h = 2 * (p & 7) + (jj >> 7);
  int b = jj & 127;
  __shared__ __align__(16) u16 kS[352 * 40];   // rows=tok, 80 B rows (odd*16B)
  __shared__ __align__(16) u16 vT[32 * 370];   // [d][tok]
  int tid = threadIdx.x;

  for (int idx = tid; idx < 352 * 4; idx += 256) {
    int row = idx >> 2, seg = idx & 3;
    uint4 vk = {0, 0, 0, 0};
    if (row < NTOK)
      vk = *reinterpret_cast<const uint4*>(qkv + (size_t)(b * NTOK + row) * 1536 + 512 +
                                           h * 32 + seg * 8);
    *reinterpret_cast<uint4*>(kS + row * 40 + seg * 8) = vk;
  }
  for (int idx = tid; idx < NTOK * 4; idx += 256) {
    int row = idx >> 2, seg = idx & 3;
    size_t base = (size_t)(b * NTOK + row) * 1536 + 1024 + h * 32 + seg * 8;
    uint4 vv = *reinterpret_cast<const uint4*>(qkv + base);
    const u16* e = reinterpret_cast<const u16*>(&vv);
#pragma unroll
    for (int t = 0; t < 8; ++t) vT[(seg * 8 + t) * 370 + row] = e[t];
  }
  for (int idx = tid; idx < 32 * 9; idx += 256) vT[(idx / 9) * 370 + NTOK + (idx % 9)] = 0;
  __syncthreads();

  int w = tid >> 6, l = tid & 63;
  const int d32 = l & 31, hi = l >> 5;
  const bool upHalf = (hi != 0);
  const f32x16 z16 = {0, 0, 0, 0, 0, 0, 0, 0, 0, 0, 0, 0, 0, 0, 0, 0};

  for (int tq = w; tq < 11; tq += 4) {
    int qrow = tq * 32 + d32;
    short8 bq0 = (short8){0, 0, 0, 0, 0, 0, 0, 0};
    short8 bq1 = (short8){0, 0, 0, 0, 0, 0, 0, 0};
    if (qrow < NTOK) {
      const u16* qb = qkv + (size_t)(b * NTOK + qrow) * 1536 + h * 32 + hi * 8;
      bq0 = *reinterpret_cast<const short8*>(qb);
      bq1 = *reinterpret_cast<const short8*>(qb + 16);
    }
    f32x16 O = z16;
    float tot = 0.f;
    const u16* bbase = biasB + ((size_t)(h * 121 + tq)) * 1024 + l * 16;  // + nt*11*1024

    // ---- prologue: S and bias for nt = 0 ----
    f32x16 S;
    short8 bb0, bb1;
    {
      const u16* kr = kS + (d32)*40 + hi * 8;
      short8 ak0 = *reinterpret_cast<const short8*>(kr);
      short8 ak1 = *reinterpret_cast<const short8*>(kr + 16);
      S = __builtin_amdgcn_mfma_f32_32x32x16_bf16(ak0, bq0, z16, 0, 0, 0);
      S = __builtin_amdgcn_mfma_f32_32x32x16_bf16(ak1, bq1, S, 0, 0, 0);
      bb0 = *reinterpret_cast<const short8*>(bbase);
      bb1 = *reinterpret_cast<const short8*>(bbase + 8);
    }

    for (int nt = 0; nt < 11; ++nt) {
      // ---- stage 2: issue S(nt+1) MFMAs + bias prefetch BEFORE softmax of nt ----
      f32x16 Sn = z16;
      short8 bb0n = bb0, bb1n = bb1;
      if (nt + 1 < 11) {
        const u16* krn = kS + ((nt + 1) * 32 + d32) * 40 + hi * 8;
        short8 a0n = *reinterpret_cast<const short8*>(krn);
        short8 a1n = *reinterpret_cast<const short8*>(krn + 16);
        const u16* bpn = bbase + (size_t)(nt + 1) * 11 * 1024;
        bb0n = *reinterpret_cast<const short8*>(bpn);
        bb1n = *reinterpret_cast<const short8*>(bpn + 8);
        Sn = __builtin_amdgcn_mfma_f32_32x32x16_bf16(a0n, bq0, Sn, 0, 0, 0);
        Sn = __builtin_amdgcn_mfma_f32_32x32x16_bf16(a1n, bq1, Sn, 0, 0, 0);
      }
      // ---- softmax + pack + half-exchange + PV for nt (overlaps Sn in MFMA pipe) ----
      float ex[16];
#pragma unroll
      for (int r = 0; r < 16; ++r) {
        u16 bw = (u16)((r < 8) ? bb0[r] : bb1[r - 8]);
        float v = S[r] + bf2f(bw);
        ex[r] = __builtin_amdgcn_exp2f(v);
        tot += ex[r];
      }
      unsigned W[8];
#pragma unroll
      for (int r2 = 0; r2 < 8; ++r2) W[r2] = cvtpk(ex[2 * r2], ex[2 * r2 + 1]);
#pragma unroll
      for (int c = 0; c < 2; ++c) {
        unsigned x0 = W[4 * c + 0], x1 = W[4 * c + 1];
        unsigned y0 = W[4 * c + 2], y1 = W[4 * c + 3];
        unsigned x0s = (unsigned)__shfl_xor((int)x0, 32);
        unsigned x1s = (unsigned)__shfl_xor((int)x1, 32);
        unsigned y0s = (unsigned)__shfl_xor((int)y0, 32);
        unsigned y1s = (unsigned)__shfl_xor((int)y1, 32);
        uint4v ap;
        ap.x = upHalf ? y0s : x0;   // elems 0,1 (from lower-half source)
        ap.y = upHalf ? y1s : x1;   // elems 2,3
        ap.z = upHalf ? y0 : x0s;   // elems 4,5 (from upper-half source)
        ap.w = upHalf ? y1 : x1s;   // elems 6,7
        short8 bv = *reinterpret_cast<const short8*>(vT + d32 * 370 + nt * 32 + c * 16 + hi * 8);
        O = __builtin_amdgcn_mfma_f32_32x32x16_bf16(__builtin_bit_cast(short8, ap), bv, O,
                                                    0, 0, 0);
      }
      S = Sn;
      bb0 = bb0n;
      bb1 = bb1n;
    }
    tot += __builtin_bit_cast(float, __shfl_xor(__builtin_bit_cast(int, tot), 32));
    float inv = 1.0f / tot;
#pragma unroll
    for (int r = 0; r < 16; ++r) {
      int qloc = (r & 3) + 8 * (r >> 2) + 4 * hi;
      float ir = __shfl(inv, qloc);
      int q = tq * 32 + qloc;
      if (q < NTOK) {
        float ov = O[r] * ir;
        outA[(size_t)(b * NTOK + q) * 512 + h * 32 + d32] = (u16)cvtpk(ov, ov);
      }
    }
  }
}

extern "C" void kernel_launch(void* const* d_in, const int* in_sizes, int n_in,
                              void* d_out, int out_size, void* d_ws, size_t ws_size,
                              hipStream_t stream) {
  const float* x      = (const float*)d_in[0];
  // d_in[1] = q_global: unused by reference
  const float* qkv_w  = (const float*)d_in[2];
  const float* qkv_b  = (const float*)d_in[3];
  const float* table  = (const float*)d_in[4];
  const float* proj_w = (const float*)d_in[5];
  const float* proj_b = (const float*)d_in[6];
  const int*   relidx = (const int*)d_in[7];

  char* ws = (char*)d_ws;
  u16*   x_bf  = (u16*)(ws);                 // 44,957,696 B (x bf16, reused as attn-out)
  u16*   qw_bf = (u16*)(ws + 44957696);      //  1,572,864 B
  u16*   pw_bf = (u16*)(ws + 46530560);      //    524,288 B
  u16*   qkv_o = (u16*)(ws + 47054848);      // 134,873,088 B
  u16*   biasB = (u16*)(ws + 181927936);     //  3,964,928 B (16*11*11*1024 u16)

  cvt_f32_bf16_k<<<2048, 256, 0, stream>>>(x, x_bf, (BATCH * NTOK * DIMC) / 4);
  prep_k<<<2960, 256, 0, stream>>>(qkv_w, qw_bf, proj_w, pw_bf, table, relidx, biasB);

  gemm_bt_k<0><<<343 * 12, 256, 0, stream>>>(x_bf, qw_bf, qkv_b, qkv_o, 1536, 512);
  attn_k<<<BATCH * HEADS_, 256, 0, stream>>>(qkv_o, biasB, x_bf);
  gemm_bt_k<1><<<343 * 4, 256, 0, stream>>>(x_bf, pw_bf, proj_b, d_out, 512, 512);
}